// Round 6
// baseline (547.446 us; speedup 1.0000x reference)
//
#include <hip/hip_runtime.h>

// ---------------------------------------------------------------------------
// out = 0.5*F + 0.5*softmax((F Wq^T)(M Wk^T)^T) M ;  N=M=8192, H=512, fp32.
// R6: R4 flash structure (K+V both through LDS, 32-key tiles, stride-36 plds)
// + K-DMA software pipeline (K(t+1) issued post-B3, drains warm at B1) +
// fused prep kernel (proj with inline W cast, packv) -> 3 dispatches.
// ---------------------------------------------------------------------------

typedef _Float16 half8 __attribute__((ext_vector_type(8)));
typedef float floatx4 __attribute__((ext_vector_type(4)));

#define MFMA16(a, b, c) __builtin_amdgcn_mfma_f32_16x16x32_f16((a), (b), (c), 0, 0, 0)

static constexpr int H = 512;
static constexpr int NROWS = 8192;

__device__ __forceinline__ void dma16(half8* lds_dst, const void* g_src) {
    __builtin_amdgcn_global_load_lds(
        (const __attribute__((address_space(1))) unsigned int*)g_src,
        (__attribute__((address_space(3))) unsigned int*)lds_dst,
        16, 0, 0);
}

// ---------------------------------------------------------------------------
// K0: fused prep.  z=0: q16 = fp16(F@Wq^T+bq);  z=1: k16 = fp16(Mem@Wk^T+bk)
// (W cast fp32->fp16 done inline);  z=2,3: pack V into MFMA B-frag order:
// V[key=kb*32+g*8+j][d=db*16+c] -> vp8[kb*2048 + db*64 + g*16+c][j]
// ---------------------------------------------------------------------------
__global__ __launch_bounds__(256, 4)
void prep_kernel(const float* __restrict__ F, const float* __restrict__ Mem,
                 const float* __restrict__ Wq, const float* __restrict__ bq,
                 const float* __restrict__ Wk, const float* __restrict__ bk,
                 _Float16* __restrict__ q16, _Float16* __restrict__ k16,
                 half8* __restrict__ vp) {
    const int z = blockIdx.z;
    if (z >= 2) {
        int b = (z - 2) * 1024 + blockIdx.y * 128 + blockIdx.x;  // 0..2047
        int cid = b * 256 + threadIdx.x;
        int kb  = cid >> 11;
        int rem = cid & 2047;
        int db  = rem >> 6;
        int gc  = rem & 63;
        int g   = gc >> 4, c = gc & 15;
        const float* src = Mem + (size_t)(kb * 32 + g * 8) * H + db * 16 + c;
        half8 v;
#pragma unroll
        for (int j = 0; j < 8; ++j) v[j] = (_Float16)src[(size_t)j * H];
        vp[cid] = v;
        return;
    }

    const float* X    = z ? Mem : F;
    const float* Wf   = z ? Wk : Wq;
    const float* bias = z ? bk : bq;
    _Float16* out     = z ? k16 : q16;

    const int lane = threadIdx.x & 63;
    const int wave = threadIdx.x >> 6;
    const int row0 = blockIdx.x * 64 + wave * 16;
    const int col0 = blockIdx.y * 64;
    const int lr = lane & 15, lq = lane >> 4;

    floatx4 acc[4];
#pragma unroll
    for (int nt = 0; nt < 4; ++nt) { acc[nt][0] = 0.f; acc[nt][1] = 0.f; acc[nt][2] = 0.f; acc[nt][3] = 0.f; }

    const float* arow = X + (size_t)(row0 + lr) * H + lq * 8;

#pragma unroll
    for (int kk = 0; kk < 16; ++kk) {
        floatx4 a0 = *(const floatx4*)(arow + kk * 32);
        floatx4 a1 = *(const floatx4*)(arow + kk * 32 + 4);
        half8 af;
        af[0] = (_Float16)a0[0]; af[1] = (_Float16)a0[1];
        af[2] = (_Float16)a0[2]; af[3] = (_Float16)a0[3];
        af[4] = (_Float16)a1[0]; af[5] = (_Float16)a1[1];
        af[6] = (_Float16)a1[2]; af[7] = (_Float16)a1[3];
#pragma unroll
        for (int nt = 0; nt < 4; ++nt) {
            const float* wrow = Wf + (size_t)(col0 + nt * 16 + lr) * H + kk * 32 + lq * 8;
            floatx4 w0 = *(const floatx4*)wrow;
            floatx4 w1 = *(const floatx4*)(wrow + 4);
            half8 bf;
            bf[0] = (_Float16)w0[0]; bf[1] = (_Float16)w0[1];
            bf[2] = (_Float16)w0[2]; bf[3] = (_Float16)w0[3];
            bf[4] = (_Float16)w1[0]; bf[5] = (_Float16)w1[1];
            bf[6] = (_Float16)w1[2]; bf[7] = (_Float16)w1[3];
            acc[nt] = MFMA16(af, bf, acc[nt]);
        }
    }
#pragma unroll
    for (int nt = 0; nt < 4; ++nt) {
        int col = col0 + nt * 16 + lr;
        float bv = bias[col];
#pragma unroll
        for (int r = 0; r < 4; ++r) {
            int row = row0 + lq * 4 + r;
            out[(size_t)row * H + col] = (_Float16)(acc[nt][r] + bv);
        }
    }
}

// ---------------------------------------------------------------------------
// K2: flash attention. blockIdx.x = rbk*4+slice; 64 q-rows per block, slice
// owns 2048 keys as 64 tiles of 32. QK: wave = 16-row stripe (K from LDS,
// B-frag-packed by the DMA's source scatter). PV: wave = 128-wide d-slice.
// Trigger softmax (m bumps only when tile max exceeds m+10). K-DMA for tile
// t+1 issues right after B3(t), flying during PV(t), drained warm at B1.
// ---------------------------------------------------------------------------
__global__ __launch_bounds__(256, 2)
void flash_kernel(const _Float16* __restrict__ q16, const _Float16* __restrict__ k16,
                  const half8* __restrict__ vp, _Float16* __restrict__ opart,
                  float* __restrict__ mpart, float* __restrict__ lpart) {
    __shared__ half8 klds[2048];          // 32 KB: K tile (32 keys), B-frag order
    __shared__ half8 vlds[2048];          // 32 KB: V tile (32 keys), packed
    __shared__ _Float16 plds[64 * 36];    // 64 rows x 32 keys, stride 36
    __shared__ float alds[64];
    __shared__ float llds[64];
    __shared__ int flagld;

    const int tid = threadIdx.x;
    const int lane = tid & 63;
    const int wave = tid >> 6;
    const int rbk = blockIdx.x >> 2;
    const int slice = blockIdx.x & 3;
    const int row0 = rbk * 64;
    const int lr = lane & 15, lq = lane >> 4;

    // K-DMA source scatter: LDS dst half8 d = tid+i*256 -> (c,kk,g,cc);
    // src halves offset = key (c*16+cc) * 512 + kk*32 + g*8 within 32-key tile.
    int koff[8];
#pragma unroll
    for (int i = 0; i < 8; ++i) {
        int d = tid + i * 256;
        int c = d >> 10, kk = (d >> 6) & 15, g = (d >> 4) & 3, cc = d & 15;
        koff[i] = (c * 16 + cc) * 512 + kk * 32 + g * 8;
    }

    // Q stripe: lane holds q16[row0+wave*16+lr][kk*32+lq*8 ..]
    const half8* qrow = (const half8*)(q16 + (size_t)(row0 + wave * 16 + lr) * H);
    half8 qf[16];
#pragma unroll
    for (int kk = 0; kk < 16; ++kk) qf[kk] = qrow[kk * 4 + lq];

    floatx4 o[4][8];
#pragma unroll
    for (int rb = 0; rb < 4; ++rb)
#pragma unroll
        for (int f = 0; f < 8; ++f) { o[rb][f][0] = 0.f; o[rb][f][1] = 0.f; o[rb][f][2] = 0.f; o[rb][f][3] = 0.f; }
    float m[4], l[4];
#pragma unroll
    for (int r = 0; r < 4; ++r) { m[r] = -1e30f; l[r] = 0.f; }

    const int kt0 = slice * 64, kt1 = kt0 + 64;

    // Prologue: K-DMA for the first tile (drained at the loop's first B1).
    {
        const _Float16* ksrc = k16 + (size_t)kt0 * 16384;
#pragma unroll
        for (int i = 0; i < 8; ++i) dma16(&klds[tid + i * 256], ksrc + koff[i]);
    }

    for (int kt = kt0; kt < kt1; ++kt) {
        __syncthreads();                                   // B1: K(kt) drained (flew during
                                                           // prev PV); vlds/plds free
        if (tid == 0) flagld = 0;

        const half8* vsrc = vp + (size_t)kt * 2048;
#pragma unroll
        for (int i = 0; i < 8; ++i) dma16(&vlds[tid + i * 256], &vsrc[tid + i * 256]);

        __syncthreads();                                   // B2: V(kt) drained

        // ---- QK^T: S[16 x 32] per wave, K frags from LDS ----
        floatx4 s0 = {0.f, 0.f, 0.f, 0.f}, s1 = {0.f, 0.f, 0.f, 0.f};
#pragma unroll
        for (int kk = 0; kk < 16; ++kk) {
            s0 = MFMA16(qf[kk], klds[kk * 64 + lane], s0);
            s1 = MFMA16(qf[kk], klds[1024 + kk * 64 + lane], s1);
        }

        // ---- trigger check (no shuffles on common path) ----
        float tm[4]; int trig = 0;
#pragma unroll
        for (int r = 0; r < 4; ++r) {
            tm[r] = fmaxf(s0[r], s1[r]);
            trig |= (tm[r] > m[r] + 10.f) ? 1 : 0;
        }
        if (__any(trig)) {
            float al[4];
#pragma unroll
            for (int r = 0; r < 4; ++r) {
                float mx = tm[r];
                mx = fmaxf(mx, __shfl_xor(mx, 1));
                mx = fmaxf(mx, __shfl_xor(mx, 2));
                mx = fmaxf(mx, __shfl_xor(mx, 4));
                mx = fmaxf(mx, __shfl_xor(mx, 8));
                float mn = (mx > m[r] + 10.f) ? mx : m[r];
                al[r] = __expf(m[r] - mn);
                m[r] = mn;
                l[r] *= al[r];
            }
            if (lr == 0) {
#pragma unroll
                for (int r = 0; r < 4; ++r) alds[wave * 16 + lq * 4 + r] = al[r];
            }
            if (lane == 0) flagld = 1;
        } else {
            if (lr == 0) {
#pragma unroll
                for (int r = 0; r < 4; ++r) alds[wave * 16 + lq * 4 + r] = 1.0f;
            }
        }

        // ---- exp, lane-local l, P -> LDS (stride 36: conflict-free) ----
#pragma unroll
        for (int r = 0; r < 4; ++r) {
            int prow = (wave * 16 + lq * 4 + r) * 36;
            float p0 = __expf(s0[r] - m[r]);
            float p1 = __expf(s1[r] - m[r]);
            l[r] += p0 + p1;
            plds[prow + lr]      = (_Float16)p0;
            plds[prow + 16 + lr] = (_Float16)p1;
        }

        __syncthreads();                                   // B3: P + alds ready; klds dead

        // ---- pipeline: issue K-DMA for tile kt+1 (flies during PV) ----
        if (kt + 1 < kt1) {
            const _Float16* ksrc2 = k16 + (size_t)(kt + 1) * 16384;
#pragma unroll
            for (int i = 0; i < 8; ++i) dma16(&klds[tid + i * 256], ksrc2 + koff[i]);
        }

        if (flagld) {
#pragma unroll
            for (int rb = 0; rb < 4; ++rb)
#pragma unroll
                for (int rr = 0; rr < 4; ++rr) {
                    float a = alds[rb * 16 + lq * 4 + rr];
#pragma unroll
                    for (int f = 0; f < 8; ++f) o[rb][f][rr] *= a;
                }
        }

        // ---- PV: wave owns d-slice [wave*128, +128) ----
        half8 pf[4];
#pragma unroll
        for (int rb = 0; rb < 4; ++rb)
            pf[rb] = *(const half8*)&plds[(rb * 16 + lr) * 36 + lq * 8];
#pragma unroll
        for (int f = 0; f < 8; ++f) {
            half8 vf = vlds[(wave * 8 + f) * 64 + lane];
#pragma unroll
            for (int rb = 0; rb < 4; ++rb) o[rb][f] = MFMA16(pf[rb], vf, o[rb][f]);
        }
    }

    // ---- final l reduction over the 16 lr lanes ----
#pragma unroll
    for (int r = 0; r < 4; ++r) {
        float lv = l[r];
        lv += __shfl_xor(lv, 1); lv += __shfl_xor(lv, 2);
        lv += __shfl_xor(lv, 4); lv += __shfl_xor(lv, 8);
        l[r] = lv;
    }
    if (lr == 0) {
#pragma unroll
        for (int r = 0; r < 4; ++r) {
            int row = wave * 16 + lq * 4 + r;
            llds[row] = l[r];
            mpart[slice * NROWS + row0 + row] = m[r];
            lpart[slice * NROWS + row0 + row] = l[r];
        }
    }
    __syncthreads();

    // ---- normalized O store (fp16) ----
    _Float16* ob = opart + (size_t)slice * NROWS * H;
#pragma unroll
    for (int rb = 0; rb < 4; ++rb) {
#pragma unroll
        for (int rr = 0; rr < 4; ++rr) {
            float linv = 1.0f / llds[rb * 16 + lq * 4 + rr];
            size_t row = row0 + rb * 16 + lq * 4 + rr;
#pragma unroll
            for (int f = 0; f < 8; ++f)
                ob[row * H + wave * 128 + f * 16 + lr] = (_Float16)(o[rb][f][rr] * linv);
        }
    }
}

// ---------------------------------------------------------------------------
// K3: merge normalized slice partials, weight = e^{m_s - max} * l_s.
// ---------------------------------------------------------------------------
__global__ void merge_kernel(const _Float16* __restrict__ opart, const float* __restrict__ mpart,
                             const float* __restrict__ lpart, const float* __restrict__ F,
                             float* __restrict__ out) {
    int idx = blockIdx.x * 256 + threadIdx.x;
    int row = idx >> 9;
    float m0 = mpart[row], m1 = mpart[NROWS + row], m2 = mpart[2 * NROWS + row], m3 = mpart[3 * NROWS + row];
    float ms = fmaxf(fmaxf(m0, m1), fmaxf(m2, m3));
    float w0 = __expf(m0 - ms) * lpart[row];
    float w1 = __expf(m1 - ms) * lpart[NROWS + row];
    float w2 = __expf(m2 - ms) * lpart[2 * NROWS + row];
    float w3 = __expf(m3 - ms) * lpart[3 * NROWS + row];
    float denom = w0 + w1 + w2 + w3;
    size_t stride = (size_t)NROWS * H;
    float num = w0 * (float)opart[idx] + w1 * (float)opart[stride + idx] +
                w2 * (float)opart[2 * stride + idx] + w3 * (float)opart[3 * stride + idx];
    out[idx] = 0.5f * F[idx] + 0.5f * (num / denom);
}

// ---------------------------------------------------------------------------
// Workspace (~57 MB):
//   [ 0M,  8M) q16   [ 8M, 16M) k16   [16M, 24M) vp   [24M, 56M) opart fp16
//   [56M,+128K) mpart  [+128K,+128K) lpart
// ---------------------------------------------------------------------------
extern "C" void kernel_launch(void* const* d_in, const int* in_sizes, int n_in,
                              void* d_out, int out_size, void* d_ws, size_t ws_size,
                              hipStream_t stream) {
    const float* F   = (const float*)d_in[0];
    const float* Mem = (const float*)d_in[1];
    const float* Wq  = (const float*)d_in[2];
    const float* bq  = (const float*)d_in[3];
    const float* Wk  = (const float*)d_in[4];
    const float* bk  = (const float*)d_in[5];
    float* out = (float*)d_out;

    char* ws = (char*)d_ws;
    _Float16* q16   = (_Float16*)(ws);
    _Float16* k16   = (_Float16*)(ws + (8ull << 20));
    half8*    vp    = (half8*)(ws + (16ull << 20));
    _Float16* opart = (_Float16*)(ws + (24ull << 20));
    float*    mpart = (float*)(ws + (56ull << 20));
    float*    lpart = (float*)(ws + (56ull << 20) + (128ull << 10));

    prep_kernel<<<dim3(128, 8, 4), 256, 0, stream>>>(F, Mem, Wq, bq, Wk, bk, q16, k16, vp);
    flash_kernel<<<512, 256, 0, stream>>>(q16, k16, vp, opart, mpart, lpart);
    merge_kernel<<<16384, 256, 0, stream>>>(opart, mpart, lpart, F, out);
}

// Round 7
// 469.354 us; speedup vs baseline: 1.1664x; 1.1664x over previous
//
#include <hip/hip_runtime.h>

// ---------------------------------------------------------------------------
// out = 0.5*F + 0.5*softmax((F Wq^T)(M Wk^T)^T) M ;  N=M=8192, H=512, fp32.
// R7: flash with 2-barrier rotated pipeline — V DMA covered by QK+softmax,
// K(t+1) DMA covered by PV. K+V both through LDS (32-key tiles, stride-36
// plds). Vectorized merge. 4 dispatches.
// ---------------------------------------------------------------------------

typedef _Float16 half8 __attribute__((ext_vector_type(8)));
typedef float floatx4 __attribute__((ext_vector_type(4)));

#define MFMA16(a, b, c) __builtin_amdgcn_mfma_f32_16x16x32_f16((a), (b), (c), 0, 0, 0)

static constexpr int H = 512;
static constexpr int NROWS = 8192;

__device__ __forceinline__ void dma16(half8* lds_dst, const void* g_src) {
    __builtin_amdgcn_global_load_lds(
        (const __attribute__((address_space(1))) unsigned int*)g_src,
        (__attribute__((address_space(3))) unsigned int*)lds_dst,
        16, 0, 0);
}

// ---------------------------------------------------------------------------
// K0: fused  (blocks 0..2047: pack V to B-frag order; 2048..4095: cast W).
// V[key=kb*32+g*8+j][d=db*16+c] -> vp8[kb*2048 + db*64 + g*16+c][j]
// ---------------------------------------------------------------------------
__global__ void packcast_kernel(const float* __restrict__ mem, half8* __restrict__ vp,
                                const float* __restrict__ wq, const float* __restrict__ wk,
                                _Float16* __restrict__ wq16, _Float16* __restrict__ wk16) {
    int b = blockIdx.x;
    if (b < 2048) {
        int cid = b * 256 + threadIdx.x;
        int kb  = cid >> 11;
        int rem = cid & 2047;
        int db  = rem >> 6;
        int gc  = rem & 63;
        int g   = gc >> 4, c = gc & 15;
        const float* src = mem + (size_t)(kb * 32 + g * 8) * H + db * 16 + c;
        half8 v;
#pragma unroll
        for (int j = 0; j < 8; ++j) v[j] = (_Float16)src[(size_t)j * H];
        vp[cid] = v;
    } else {
        int i = (b - 2048) * 256 + threadIdx.x;
        if (i < 262144) wq16[i] = (_Float16)wq[i];
        else            wk16[i - 262144] = (_Float16)wk[i - 262144];
    }
}

// ---------------------------------------------------------------------------
// K1: both projections (z=0: q = F@Wq^T+bq ; z=1: k = M@Wk^T+bk), fp16 out.
// ---------------------------------------------------------------------------
__global__ __launch_bounds__(256, 4)
void proj_kernel(const float* __restrict__ X0, const _Float16* __restrict__ W0,
                 const float* __restrict__ b0, _Float16* __restrict__ out0,
                 const float* __restrict__ X1, const _Float16* __restrict__ W1,
                 const float* __restrict__ b1, _Float16* __restrict__ out1) {
    const float* X = blockIdx.z ? X1 : X0;
    const _Float16* W16 = blockIdx.z ? W1 : W0;
    const float* bias = blockIdx.z ? b1 : b0;
    _Float16* out = blockIdx.z ? out1 : out0;

    const int lane = threadIdx.x & 63;
    const int wave = threadIdx.x >> 6;
    const int row0 = blockIdx.x * 64 + wave * 16;
    const int col0 = blockIdx.y * 64;
    const int lr = lane & 15, lq = lane >> 4;

    floatx4 acc[4];
#pragma unroll
    for (int nt = 0; nt < 4; ++nt) { acc[nt][0] = 0.f; acc[nt][1] = 0.f; acc[nt][2] = 0.f; acc[nt][3] = 0.f; }

    const float* arow = X + (size_t)(row0 + lr) * H + lq * 8;
    const half8* wbase = (const half8*)W16;

#pragma unroll
    for (int kk = 0; kk < 16; ++kk) {
        floatx4 a0 = *(const floatx4*)(arow + kk * 32);
        floatx4 a1 = *(const floatx4*)(arow + kk * 32 + 4);
        half8 af;
        af[0] = (_Float16)a0[0]; af[1] = (_Float16)a0[1];
        af[2] = (_Float16)a0[2]; af[3] = (_Float16)a0[3];
        af[4] = (_Float16)a1[0]; af[5] = (_Float16)a1[1];
        af[6] = (_Float16)a1[2]; af[7] = (_Float16)a1[3];
#pragma unroll
        for (int nt = 0; nt < 4; ++nt) {
            half8 bf = wbase[(size_t)(col0 + nt * 16 + lr) * 64 + kk * 4 + lq];
            acc[nt] = MFMA16(af, bf, acc[nt]);
        }
    }
#pragma unroll
    for (int nt = 0; nt < 4; ++nt) {
        int col = col0 + nt * 16 + lr;
        float bv = bias[col];
#pragma unroll
        for (int r = 0; r < 4; ++r) {
            int row = row0 + lq * 4 + r;
            out[(size_t)row * H + col] = (_Float16)(acc[nt][r] + bv);
        }
    }
}

// ---------------------------------------------------------------------------
// K2: flash attention. blockIdx.x = rbk*4+slice; 64 q-rows per block, slice
// owns 2048 keys as 64 tiles of 32. QK: wave = 16-row stripe (K from LDS,
// B-frag-packed by the DMA source scatter). PV: wave = 128-wide d-slice.
// Trigger softmax (m bumps only when tile max exceeds m+10; e^10 < fp16 max).
// 2-barrier rotated pipeline:
//   B1 drains K(t) [covered by PV(t-1)]; issue V(t); QK+softmax [covers V];
//   B2 drains V(t), publishes P, klds dead; issue K(t+1); PV [covers K].
// ---------------------------------------------------------------------------
__global__ __launch_bounds__(256, 2)
void flash_kernel(const _Float16* __restrict__ q16, const _Float16* __restrict__ k16,
                  const half8* __restrict__ vp, _Float16* __restrict__ opart,
                  float* __restrict__ mpart, float* __restrict__ lpart) {
    __shared__ half8 klds[2048];          // 32 KB: K tile (32 keys), B-frag order
    __shared__ half8 vlds[2048];          // 32 KB: V tile (32 keys), packed
    __shared__ _Float16 plds[64 * 36];    // 64 rows x 32 keys, stride 36
    __shared__ float alds[64];
    __shared__ float llds[64];
    __shared__ int flagld;

    const int tid = threadIdx.x;
    const int lane = tid & 63;
    const int wave = tid >> 6;
    const int rbk = blockIdx.x >> 2;
    const int slice = blockIdx.x & 3;
    const int row0 = rbk * 64;
    const int lr = lane & 15, lq = lane >> 4;

    // K-DMA source scatter: LDS dst half8 d = tid+i*256 -> (c,kk,g,cc);
    // src halves offset = key (c*16+cc) * 512 + kk*32 + g*8 within 32-key tile.
    int koff[8];
#pragma unroll
    for (int i = 0; i < 8; ++i) {
        int d = tid + i * 256;
        int c = d >> 10, kk = (d >> 6) & 15, g = (d >> 4) & 3, cc = d & 15;
        koff[i] = (c * 16 + cc) * 512 + kk * 32 + g * 8;
    }

    // Q stripe: lane holds q16[row0+wave*16+lr][kk*32+lq*8 ..]
    const half8* qrow = (const half8*)(q16 + (size_t)(row0 + wave * 16 + lr) * H);
    half8 qf[16];
#pragma unroll
    for (int kk = 0; kk < 16; ++kk) qf[kk] = qrow[kk * 4 + lq];

    floatx4 o[4][8];
#pragma unroll
    for (int rb = 0; rb < 4; ++rb)
#pragma unroll
        for (int f = 0; f < 8; ++f) { o[rb][f][0] = 0.f; o[rb][f][1] = 0.f; o[rb][f][2] = 0.f; o[rb][f][3] = 0.f; }
    float m[4], l[4];
#pragma unroll
    for (int r = 0; r < 4; ++r) { m[r] = -1e30f; l[r] = 0.f; }

    const int kt0 = slice * 64, kt1 = kt0 + 64;

    // Prologue: K-DMA for the first tile (drained at the loop's first B1).
    {
        const _Float16* ksrc = k16 + (size_t)kt0 * 16384;
#pragma unroll
        for (int i = 0; i < 8; ++i) dma16(&klds[tid + i * 256], ksrc + koff[i]);
    }

    for (int kt = kt0; kt < kt1; ++kt) {
        __syncthreads();                          // B1: K(kt) drained; vlds/plds free
        if (tid == 0) flagld = 0;

        // ---- issue V(kt) DMA; flies during QK+softmax ----
        const half8* vsrc = vp + (size_t)kt * 2048;
#pragma unroll
        for (int i = 0; i < 8; ++i) dma16(&vlds[tid + i * 256], &vsrc[tid + i * 256]);

        // ---- QK^T: S[16 x 32] per wave, K frags from LDS ----
        floatx4 s0 = {0.f, 0.f, 0.f, 0.f}, s1 = {0.f, 0.f, 0.f, 0.f};
#pragma unroll
        for (int kk = 0; kk < 16; ++kk) {
            s0 = MFMA16(qf[kk], klds[kk * 64 + lane], s0);
            s1 = MFMA16(qf[kk], klds[1024 + kk * 64 + lane], s1);
        }

        // ---- trigger check (no shuffles on common path) ----
        float tm[4]; int trig = 0;
#pragma unroll
        for (int r = 0; r < 4; ++r) {
            tm[r] = fmaxf(s0[r], s1[r]);
            trig |= (tm[r] > m[r] + 10.f) ? 1 : 0;
        }
        if (__any(trig)) {
            float al[4];
#pragma unroll
            for (int r = 0; r < 4; ++r) {
                float mx = tm[r];
                mx = fmaxf(mx, __shfl_xor(mx, 1));
                mx = fmaxf(mx, __shfl_xor(mx, 2));
                mx = fmaxf(mx, __shfl_xor(mx, 4));
                mx = fmaxf(mx, __shfl_xor(mx, 8));
                float mn = (mx > m[r] + 10.f) ? mx : m[r];
                al[r] = __expf(m[r] - mn);
                m[r] = mn;
                l[r] *= al[r];
            }
            if (lr == 0) {
#pragma unroll
                for (int r = 0; r < 4; ++r) alds[wave * 16 + lq * 4 + r] = al[r];
            }
            if (lane == 0) flagld = 1;
        } else {
            if (lr == 0) {
#pragma unroll
                for (int r = 0; r < 4; ++r) alds[wave * 16 + lq * 4 + r] = 1.0f;
            }
        }

        // ---- exp, lane-local l, P -> LDS (stride 36: conflict-free) ----
#pragma unroll
        for (int r = 0; r < 4; ++r) {
            int prow = (wave * 16 + lq * 4 + r) * 36;
            float p0 = __expf(s0[r] - m[r]);
            float p1 = __expf(s1[r] - m[r]);
            l[r] += p0 + p1;
            plds[prow + lr]      = (_Float16)p0;
            plds[prow + 16 + lr] = (_Float16)p1;
        }

        __syncthreads();                          // B2: V(kt) drained; P/alds
                                                  // published; klds dead

        // ---- issue K(kt+1) DMA; flies during PV ----
        if (kt + 1 < kt1) {
            const _Float16* ksrc2 = k16 + (size_t)(kt + 1) * 16384;
#pragma unroll
            for (int i = 0; i < 8; ++i) dma16(&klds[tid + i * 256], ksrc2 + koff[i]);
        }

        if (flagld) {
#pragma unroll
            for (int rb = 0; rb < 4; ++rb)
#pragma unroll
                for (int rr = 0; rr < 4; ++rr) {
                    float a = alds[rb * 16 + lq * 4 + rr];
#pragma unroll
                    for (int f = 0; f < 8; ++f) o[rb][f][rr] *= a;
                }
        }

        // ---- PV: wave owns d-slice [wave*128, +128) ----
        half8 pf[4];
#pragma unroll
        for (int rb = 0; rb < 4; ++rb)
            pf[rb] = *(const half8*)&plds[(rb * 16 + lr) * 36 + lq * 8];
#pragma unroll
        for (int f = 0; f < 8; ++f) {
            half8 vf = vlds[(wave * 8 + f) * 64 + lane];
#pragma unroll
            for (int rb = 0; rb < 4; ++rb) o[rb][f] = MFMA16(pf[rb], vf, o[rb][f]);
        }
    }

    // ---- final l reduction over the 16 lr lanes ----
#pragma unroll
    for (int r = 0; r < 4; ++r) {
        float lv = l[r];
        lv += __shfl_xor(lv, 1); lv += __shfl_xor(lv, 2);
        lv += __shfl_xor(lv, 4); lv += __shfl_xor(lv, 8);
        l[r] = lv;
    }
    if (lr == 0) {
#pragma unroll
        for (int r = 0; r < 4; ++r) {
            int row = wave * 16 + lq * 4 + r;
            llds[row] = l[r];
            mpart[slice * NROWS + row0 + row] = m[r];
            lpart[slice * NROWS + row0 + row] = l[r];
        }
    }
    __syncthreads();

    // ---- normalized O store (fp16) ----
    _Float16* ob = opart + (size_t)slice * NROWS * H;
#pragma unroll
    for (int rb = 0; rb < 4; ++rb) {
#pragma unroll
        for (int rr = 0; rr < 4; ++rr) {
            float linv = 1.0f / llds[rb * 16 + lq * 4 + rr];
            size_t row = row0 + rb * 16 + lq * 4 + rr;
#pragma unroll
            for (int f = 0; f < 8; ++f)
                ob[row * H + wave * 128 + f * 16 + lr] = (_Float16)(o[rb][f][rr] * linv);
        }
    }
}

// ---------------------------------------------------------------------------
// K3: merge normalized slice partials, weight = e^{m_s - max} * l_s.
// Vectorized: one thread = 8 contiguous outputs of one row (half8 / float4).
// ---------------------------------------------------------------------------
__global__ void merge_kernel(const _Float16* __restrict__ opart, const float* __restrict__ mpart,
                             const float* __restrict__ lpart, const float* __restrict__ F,
                             float* __restrict__ out) {
    int t = blockIdx.x * 256 + threadIdx.x;       // 0 .. 524287
    int row = t >> 6;                             // 64 threads per 512-wide row
    float m0 = mpart[row], m1 = mpart[NROWS + row], m2 = mpart[2 * NROWS + row], m3 = mpart[3 * NROWS + row];
    float ms = fmaxf(fmaxf(m0, m1), fmaxf(m2, m3));
    float w0 = __expf(m0 - ms) * lpart[row];
    float w1 = __expf(m1 - ms) * lpart[NROWS + row];
    float w2 = __expf(m2 - ms) * lpart[2 * NROWS + row];
    float w3 = __expf(m3 - ms) * lpart[3 * NROWS + row];
    float rinv = 0.5f / (w0 + w1 + w2 + w3);
    w0 *= rinv; w1 *= rinv; w2 *= rinv; w3 *= rinv;

    const half8* op8 = (const half8*)opart;       // 524288 half8 per slice
    half8 o0 = op8[t];
    half8 o1 = op8[524288 + t];
    half8 o2 = op8[2 * 524288 + t];
    half8 o3 = op8[3 * 524288 + t];
    const floatx4* F4 = (const floatx4*)F;
    floatx4 f0 = F4[2 * t], f1 = F4[2 * t + 1];
    floatx4 r0, r1;
#pragma unroll
    for (int j = 0; j < 4; ++j) {
        r0[j] = 0.5f * f0[j] + (w0 * (float)o0[j] + w1 * (float)o1[j] + w2 * (float)o2[j] + w3 * (float)o3[j]);
        r1[j] = 0.5f * f1[j] + (w0 * (float)o0[4 + j] + w1 * (float)o1[4 + j] + w2 * (float)o2[4 + j] + w3 * (float)o3[4 + j]);
    }
    floatx4* out4 = (floatx4*)out;
    out4[2 * t] = r0;
    out4[2 * t + 1] = r1;
}

// ---------------------------------------------------------------------------
// Workspace (~59 MB):
//   [ 0M,  8M) q16   [ 8M, 16M) k16   [16M, 24M) vp   [24M, 56M) opart fp16
//   [56M,+128K) mpart  [+128K,+128K) lpart  [57M,+1M) wq16/wk16
// ---------------------------------------------------------------------------
extern "C" void kernel_launch(void* const* d_in, const int* in_sizes, int n_in,
                              void* d_out, int out_size, void* d_ws, size_t ws_size,
                              hipStream_t stream) {
    const float* F   = (const float*)d_in[0];
    const float* Mem = (const float*)d_in[1];
    const float* Wq  = (const float*)d_in[2];
    const float* bq  = (const float*)d_in[3];
    const float* Wk  = (const float*)d_in[4];
    const float* bk  = (const float*)d_in[5];
    float* out = (float*)d_out;

    char* ws = (char*)d_ws;
    _Float16* q16   = (_Float16*)(ws);
    _Float16* k16   = (_Float16*)(ws + (8ull << 20));
    half8*    vp    = (half8*)(ws + (16ull << 20));
    _Float16* opart = (_Float16*)(ws + (24ull << 20));
    float*    mpart = (float*)(ws + (56ull << 20));
    float*    lpart = (float*)(ws + (56ull << 20) + (128ull << 10));
    _Float16* wq16  = (_Float16*)(ws + (57ull << 20));
    _Float16* wk16  = (_Float16*)(ws + (57ull << 20) + (512ull << 10));

    packcast_kernel<<<4096, 256, 0, stream>>>(Mem, vp, Wq, Wk, wq16, wk16);
    proj_kernel<<<dim3(128, 8, 2), 256, 0, stream>>>(F, wq16, bq, q16, Mem, wk16, bk, k16);
    flash_kernel<<<512, 256, 0, stream>>>(q16, k16, vp, opart, mpart, lpart);
    merge_kernel<<<2048, 256, 0, stream>>>(opart, mpart, lpart, F, out);
}